// Round 1
// baseline (149.091 us; speedup 1.0000x reference)
//
#include <hip/hip_runtime.h>
#include <hip/hip_bf16.h>

#define NSTACK 4
#define RANK 4
#define NIN 1024
#define NOUT 4096
#define NTOK 4096  // 2*2048 flattened tokens

typedef __bf16 bf16x8 __attribute__((ext_vector_type(8)));
typedef float f32x4 __attribute__((ext_vector_type(4)));

// ---------------- cast x fp32 -> bf16 (vectorized) ----------------
__global__ __launch_bounds__(256) void cast_x_kernel(const float* __restrict__ x,
                                                     __bf16* __restrict__ y) {
  int i = (blockIdx.x * 256 + threadIdx.x) * 8;
  float4 a = *reinterpret_cast<const float4*>(x + i);
  float4 b = *reinterpret_cast<const float4*>(x + i + 4);
  bf16x8 o;
  o[0] = (__bf16)a.x; o[1] = (__bf16)a.y; o[2] = (__bf16)a.z; o[3] = (__bf16)a.w;
  o[4] = (__bf16)b.x; o[5] = (__bf16)b.y; o[6] = (__bf16)b.z; o[7] = (__bf16)b.w;
  *reinterpret_cast<bf16x8*>(y + i) = o;
}

// ---------------- build M: one wave per (stack, diagonal) ----------------
// M[s,t,c] = sum_r sum_{j=max(0,t-c)}^{t} G[s,r,j] * H[s,r,c-t+j]
// Along diagonal d=c-t: inclusive prefix sum over k of e(k)=sum_r G[k+gofs]*H[k+hofs],
// with gofs=max(0,-d), hofs=max(0,d); t=k+gofs, c=k+hofs.
__global__ __launch_bounds__(256) void build_m_kernel(const float* __restrict__ G,
                                                      const float* __restrict__ H,
                                                      __bf16* __restrict__ M) {
  const int ndiag = 2 * NIN - 1;  // 2047
  int wid = blockIdx.x * 4 + (threadIdx.x >> 6);
  if (wid >= NSTACK * ndiag) return;
  int lane = threadIdx.x & 63;
  int s = wid / ndiag;
  int dd = wid % ndiag;
  int d = dd - (NIN - 1);
  int ad = d < 0 ? -d : d;
  int L = NIN - ad;
  int gofs = d < 0 ? -d : 0;
  int hofs = d > 0 ? d : 0;
  const float* Gs = G + s * (RANK * NIN);
  const float* Hs = H + s * (RANK * NIN);
  __bf16* Ms = M + (size_t)s * NIN * NIN;

  float carry = 0.f;
  for (int r0 = 0; r0 < L; r0 += 64) {
    int k = r0 + lane;
    float e = 0.f;
    if (k < L) {
      int gi = k + gofs, hi = k + hofs;
      e = Gs[gi] * Hs[hi]
        + Gs[NIN + gi] * Hs[NIN + hi]
        + Gs[2 * NIN + gi] * Hs[2 * NIN + hi]
        + Gs[3 * NIN + gi] * Hs[3 * NIN + hi];
    }
    // wave inclusive scan
    float v = e;
    #pragma unroll
    for (int off = 1; off < 64; off <<= 1) {
      float o = __shfl_up(v, off, 64);
      if (lane >= off) v += o;
    }
    if (k < L) {
      int t = k + gofs;
      int c = k + hofs;
      Ms[(size_t)t * NIN + c] = (__bf16)(carry + v);
    }
    carry += __shfl(v, 63, 64);
  }
}

// ---------------- GEMM: out[m][o] = sum_k xb[m][k]*Mb[o][k] + bias[o] ----------------
// 128x128 tile, 4 waves (2x2, each 64x64 via 4x4 of 16x16x32 MFMA), BK=32,
// global_load_lds width 16, 2-barrier K-loop (m97 structure).
__device__ __forceinline__ void gload16(const void* gsrc, void* lds) {
  __builtin_amdgcn_global_load_lds(
      (const __attribute__((address_space(1))) unsigned int*)gsrc,
      (__attribute__((address_space(3))) unsigned int*)lds, 16, 0, 0);
}

__global__ __launch_bounds__(256, 2) void gemm_bt_kernel(
    const __bf16* __restrict__ A,    // [NTOK][NIN] bf16
    const __bf16* __restrict__ B,    // [NOUT][NIN] bf16 (the M matrix)
    const float* __restrict__ bias,  // [NOUT]
    float* __restrict__ C) {         // [NTOK][NOUT] f32
  __shared__ __align__(16) char smem[16384];  // lA [128][32]bf16 = 8K, lB same

  const int tid = threadIdx.x;
  const int lane = tid & 63;
  const int wid = tid >> 6;
  const int wr = wid >> 1, wc = wid & 1;
  const int bn = blockIdx.x, bm = blockIdx.y;
  const int brow = bm * 128, bcol = bn * 128;

  // staging: tile is 128 rows x 64 bytes; thread t covers bytes t*16 and t*16+4096
  const int b1 = tid * 16;
  const int b2 = b1 + 4096;
  const char* Ag1 = (const char*)A + (size_t)(brow + (b1 >> 6)) * (NIN * 2) + (b1 & 63);
  const char* Ag2 = (const char*)A + (size_t)(brow + (b2 >> 6)) * (NIN * 2) + (b2 & 63);
  const char* Bg1 = (const char*)B + (size_t)(bcol + (b1 >> 6)) * (NIN * 2) + (b1 & 63);
  const char* Bg2 = (const char*)B + (size_t)(bcol + (b2 >> 6)) * (NIN * 2) + (b2 & 63);
  char* lA1 = smem + b1;
  char* lA2 = smem + b2;
  char* lB1 = smem + 8192 + b1;
  char* lB2 = smem + 8192 + b2;

  // ds_read byte offsets: A frag row = wr*64+mi*16+(lane&15), k-chunk = (lane>>4)*16B
  const int koff = (lane >> 4) * 16;
  int aoff[4], boff[4];
  #pragma unroll
  for (int mi = 0; mi < 4; ++mi)
    aoff[mi] = (wr * 64 + mi * 16 + (lane & 15)) * 64 + koff;
  #pragma unroll
  for (int ni = 0; ni < 4; ++ni)
    boff[ni] = 8192 + (wc * 64 + ni * 16 + (lane & 15)) * 64 + koff;

  f32x4 acc[4][4];
  #pragma unroll
  for (int i = 0; i < 4; ++i)
    #pragma unroll
    for (int j = 0; j < 4; ++j)
      acc[i][j] = (f32x4){0.f, 0.f, 0.f, 0.f};

  #pragma unroll 1
  for (int kt = 0; kt < NIN / 32; ++kt) {
    const int kb = kt * 64;  // byte offset in k per row
    gload16(Ag1 + kb, lA1);
    gload16(Ag2 + kb, lA2);
    gload16(Bg1 + kb, lB1);
    gload16(Bg2 + kb, lB2);
    __syncthreads();  // drains vmcnt(0): LDS tile ready

    bf16x8 af[4], bf[4];
    #pragma unroll
    for (int mi = 0; mi < 4; ++mi)
      af[mi] = *reinterpret_cast<const bf16x8*>(smem + aoff[mi]);
    #pragma unroll
    for (int ni = 0; ni < 4; ++ni)
      bf[ni] = *reinterpret_cast<const bf16x8*>(smem + boff[ni]);

    #pragma unroll
    for (int mi = 0; mi < 4; ++mi)
      #pragma unroll
      for (int ni = 0; ni < 4; ++ni)
        acc[mi][ni] = __builtin_amdgcn_mfma_f32_16x16x32_bf16(af[mi], bf[ni], acc[mi][ni], 0, 0, 0);

    __syncthreads();  // all waves done reading before next stage overwrites
  }

  // epilogue: D layout col=lane&15, row=(lane>>4)*4+reg  [guide §3, m89/m91-verified]
  #pragma unroll
  for (int ni = 0; ni < 4; ++ni) {
    const int col = bcol + wc * 64 + ni * 16 + (lane & 15);
    const float bv = bias[col];
    #pragma unroll
    for (int mi = 0; mi < 4; ++mi) {
      const int row0 = brow + wr * 64 + mi * 16 + ((lane >> 4) << 2);
      float* Cp = C + (size_t)row0 * NOUT + col;
      Cp[0 * (size_t)NOUT] = acc[mi][ni][0] + bv;
      Cp[1 * (size_t)NOUT] = acc[mi][ni][1] + bv;
      Cp[2 * (size_t)NOUT] = acc[mi][ni][2] + bv;
      Cp[3 * (size_t)NOUT] = acc[mi][ni][3] + bv;
    }
  }
}

extern "C" void kernel_launch(void* const* d_in, const int* in_sizes, int n_in,
                              void* d_out, int out_size, void* d_ws, size_t ws_size,
                              hipStream_t stream) {
  const float* x = (const float*)d_in[0];
  const float* G = (const float*)d_in[1];
  const float* H = (const float*)d_in[2];
  const float* bias = (const float*)d_in[3];
  float* out = (float*)d_out;

  __bf16* xb = (__bf16*)d_ws;                                   // 8 MB
  __bf16* Mb = (__bf16*)((char*)d_ws + (size_t)NTOK * NIN * 2); // 8 MB

  cast_x_kernel<<<(NTOK * NIN) / (256 * 8), 256, 0, stream>>>(x, xb);
  build_m_kernel<<<(NSTACK * (2 * NIN - 1) + 3) / 4, 256, 0, stream>>>(G, H, Mb);
  gemm_bt_kernel<<<dim3(NOUT / 128, NTOK / 128), 256, 0, stream>>>(xb, Mb, bias, out);
}

// Round 2
// 145.845 us; speedup vs baseline: 1.0223x; 1.0223x over previous
//
#include <hip/hip_runtime.h>
#include <hip/hip_bf16.h>

#define NIN 1024
#define NOUT 4096
#define NTOK 4096
#define NSTACK 4
#define RANK 4

typedef __bf16 bf16x8 __attribute__((ext_vector_type(8)));
typedef float f32x4 __attribute__((ext_vector_type(4)));

// ============ fused prep: cast x (blocks 0..2047) + build M (blocks 2048..4094) ============
// M[s,t,c] = sum_r sum_{i=0}^{min(t,c)} G[s,r,t-i]*H[s,r,c-i]  -> per-diagonal prefix sum.
__global__ __launch_bounds__(256) void prep_kernel(const float* __restrict__ x,
                                                   const float* __restrict__ G,
                                                   const float* __restrict__ H,
                                                   __bf16* __restrict__ xb,
                                                   __bf16* __restrict__ M) {
  int bid = blockIdx.x;
  if (bid < 2048) {  // -------- cast: 2048 blocks * 2048 elems = 4096*1024 --------
    int i = (bid * 256 + threadIdx.x) * 8;
    float4 a = *reinterpret_cast<const float4*>(x + i);
    float4 b = *reinterpret_cast<const float4*>(x + i + 4);
    bf16x8 o;
    o[0] = (__bf16)a.x; o[1] = (__bf16)a.y; o[2] = (__bf16)a.z; o[3] = (__bf16)a.w;
    o[4] = (__bf16)b.x; o[5] = (__bf16)b.y; o[6] = (__bf16)b.z; o[7] = (__bf16)b.w;
    *reinterpret_cast<bf16x8*>(xb + i) = o;
    return;
  }
  bid -= 2048;  // -------- build M: one wave per (stack, diagonal) --------
  const int ndiag = 2 * NIN - 1;  // 2047
  int wid = bid * 4 + (threadIdx.x >> 6);
  if (wid >= NSTACK * ndiag) return;
  int lane = threadIdx.x & 63;
  int s = wid / ndiag;
  int dd = wid % ndiag;
  int d = dd - (NIN - 1);
  int ad = d < 0 ? -d : d;
  int L = NIN - ad;
  int gofs = d < 0 ? -d : 0;
  int hofs = d > 0 ? d : 0;
  const float* Gs = G + s * (RANK * NIN);
  const float* Hs = H + s * (RANK * NIN);
  __bf16* Ms = M + (size_t)s * NIN * NIN;

  float carry = 0.f;
  for (int r0 = 0; r0 < L; r0 += 64) {
    int k = r0 + lane;
    float e = 0.f;
    if (k < L) {
      int gi = k + gofs, hi2 = k + hofs;
      e = Gs[gi] * Hs[hi2]
        + Gs[NIN + gi] * Hs[NIN + hi2]
        + Gs[2 * NIN + gi] * Hs[2 * NIN + hi2]
        + Gs[3 * NIN + gi] * Hs[3 * NIN + hi2];
    }
    float v = e;
    #pragma unroll
    for (int off = 1; off < 64; off <<= 1) {
      float o = __shfl_up(v, off, 64);
      if (lane >= off) v += o;
    }
    if (k < L) Ms[(size_t)(k + gofs) * NIN + (k + hofs)] = (__bf16)(carry + v);
    carry += __shfl(v, 63, 64);
  }
}

// ============ GEMM: C[m][n] = sum_k A[m][k]*B[n][k] + bias[n] ============
// BM=BN=256, BK=32, 8 waves (2Mx4N, wave tile 128x64), 3 LDS buffers (96KB),
// prefetch distance 2, counted vmcnt(4) once per K-tile, 2 phases/tile x 16 MFMA,
// T2 swizzle byte^=((row>>1)&3)<<4 (linear LDS dest + pre-swizzled global src),
// T5 setprio around MFMA, T1 XCD swizzle.
#define BM 256
#define BN 256
#define BK 32
#define ABY (BM * BK * 2)   // 16384
#define BUFBY (2 * ABY)     // 32768 (A @ +0, B @ +16384)
#define KT (NIN / BK)       // 32

__device__ __forceinline__ void gload16(const char* gsrc, char* lds) {
  __builtin_amdgcn_global_load_lds(
      (const __attribute__((address_space(1))) unsigned int*)gsrc,
      (__attribute__((address_space(3))) unsigned int*)lds, 16, 0, 0);
}

#define MEMF asm volatile("" ::: "memory")
__device__ __forceinline__ void wgbar() {
  MEMF; __builtin_amdgcn_s_barrier(); MEMF;
}

__global__ __launch_bounds__(512, 2) void gemm_kernel(
    const __bf16* __restrict__ A,   // [NTOK][NIN]
    const __bf16* __restrict__ B,   // [NOUT][NIN]
    const float* __restrict__ bias, // [NOUT]
    float* __restrict__ C) {        // [NTOK][NOUT]
  __shared__ __align__(16) char smem[3 * BUFBY];  // 96 KB

  const int tid = threadIdx.x;
  const int lane = tid & 63;
  const int lo = lane & 15;
  const int hi = lane >> 4;
  const int wid = tid >> 6;
  const int wr = wid >> 2;   // 0..1 (row half)
  const int wc = wid & 3;    // 0..3 (col quarter)

  // XCD-aware block swizzle (256 blocks, 256%8==0 -> simple bijection)
  const int orig = blockIdx.x;
  const int wg = (orig & 7) * 32 + (orig >> 3);
  const int bx = wg & 15;          // N tile
  const int by = wg >> 4;          // M tile
  const int brow = by * BM;
  const int bcol = bx * BN;

  // ---- staging addresses: LDS linear dest P, global src col = (P&63) ^ ((row>>1 &3)<<4)
  const char* Ab = (const char*)(A + (size_t)brow * NIN);
  const char* Bb = (const char*)(B + (size_t)bcol * NIN);
  size_t ag[2], bg[2];
  int al[2], bl[2];
  #pragma unroll
  for (int l = 0; l < 2; ++l) {
    int P = (l * 512 + tid) * 16;
    int row = P >> 6;
    int inner = (P & 63) ^ (((row >> 1) & 3) << 4);
    al[l] = P;
    ag[l] = (size_t)row * (NIN * 2) + inner;
    bl[l] = P;
    bg[l] = (size_t)row * (NIN * 2) + inner;
  }

  // ---- fragment ds_read offsets (swizzled): row*64 + ((hi ^ ((lo>>1)&3))<<4)
  const int kso = ((hi ^ ((lo >> 1) & 3)) << 4);
  const int abase = (wr * 128 + lo) * 64 + kso;          // + mi*1024
  const int bbase = ABY + (wc * 64 + lo) * 64 + kso;     // + ni*1024

  f32x4 acc[8][4];
  #pragma unroll
  for (int i = 0; i < 8; ++i)
    #pragma unroll
    for (int j = 0; j < 4; ++j)
      acc[i][j] = (f32x4){0.f, 0.f, 0.f, 0.f};

  // ---- prologue: stage tiles 0 and 1 ----
  #pragma unroll
  for (int l = 0; l < 2; ++l) gload16(Ab + ag[l], smem + al[l]);
  #pragma unroll
  for (int l = 0; l < 2; ++l) gload16(Bb + bg[l], smem + ABY + bl[l]);
  #pragma unroll
  for (int l = 0; l < 2; ++l) gload16(Ab + 64 + ag[l], smem + BUFBY + al[l]);
  #pragma unroll
  for (int l = 0; l < 2; ++l) gload16(Bb + 64 + bg[l], smem + BUFBY + ABY + bl[l]);
  asm volatile("s_waitcnt vmcnt(4)" ::: "memory");
  wgbar();

  int cb = 0;            // current buffer byte base
  int sb = 2 * BUFBY;    // staging buffer byte base (tile kt+2)
  #pragma unroll 1
  for (int kt = 0; kt < KT; ++kt) {
    const char* buf = smem + cb;
    const int kg = (kt + 2) * 64;
    const bool dost = (kt + 2) < KT;

    // ---------- phase 1: A rowgroups 0-3 + all B; MFMA mi 0-3 ----------
    bf16x8 af[4], bfr[4];
    #pragma unroll
    for (int mi = 0; mi < 4; ++mi)
      af[mi] = *(const bf16x8*)(buf + abase + mi * 1024);
    #pragma unroll
    for (int ni = 0; ni < 4; ++ni)
      bfr[ni] = *(const bf16x8*)(buf + bbase + ni * 1024);
    if (dost) {
      gload16(Ab + kg + ag[0], smem + sb + al[0]);
      gload16(Ab + kg + ag[1], smem + sb + al[1]);
    }
    wgbar();
    __builtin_amdgcn_s_setprio(1);
    #pragma unroll
    for (int mi = 0; mi < 4; ++mi)
      #pragma unroll
      for (int ni = 0; ni < 4; ++ni)
        acc[mi][ni] = __builtin_amdgcn_mfma_f32_16x16x32_bf16(af[mi], bfr[ni], acc[mi][ni], 0, 0, 0);
    __builtin_amdgcn_s_setprio(0);
    wgbar();

    // ---------- phase 2: A rowgroups 4-7 (B kept in regs); MFMA mi 4-7 ----------
    bf16x8 af2[4];
    #pragma unroll
    for (int mi = 0; mi < 4; ++mi)
      af2[mi] = *(const bf16x8*)(buf + abase + (mi + 4) * 1024);
    if (dost) {
      gload16(Bb + kg + bg[0], smem + sb + ABY + bl[0]);
      gload16(Bb + kg + bg[1], smem + sb + ABY + bl[1]);
    }
    if (kt < KT - 2) asm volatile("s_waitcnt vmcnt(4)" ::: "memory");
    else             asm volatile("s_waitcnt vmcnt(0)" ::: "memory");
    wgbar();
    __builtin_amdgcn_s_setprio(1);
    #pragma unroll
    for (int mi = 0; mi < 4; ++mi)
      #pragma unroll
      for (int ni = 0; ni < 4; ++ni)
        acc[mi + 4][ni] = __builtin_amdgcn_mfma_f32_16x16x32_bf16(af2[mi], bfr[ni], acc[mi + 4][ni], 0, 0, 0);
    __builtin_amdgcn_s_setprio(0);
    wgbar();

    cb += BUFBY; if (cb == 3 * BUFBY) cb = 0;
    sb += BUFBY; if (sb == 3 * BUFBY) sb = 0;
  }

  // ---- epilogue: D layout col=lane&15, row=(lane>>4)*4+reg ----
  #pragma unroll
  for (int ni = 0; ni < 4; ++ni) {
    const int col = bcol + wc * 64 + ni * 16 + lo;
    const float bv = bias[col];
    #pragma unroll
    for (int mi = 0; mi < 8; ++mi) {
      const int row0 = brow + wr * 128 + mi * 16 + hi * 4;
      float* Cp = C + (size_t)row0 * NOUT + col;
      Cp[0]                  = acc[mi][ni][0] + bv;
      Cp[(size_t)NOUT]       = acc[mi][ni][1] + bv;
      Cp[2 * (size_t)NOUT]   = acc[mi][ni][2] + bv;
      Cp[3 * (size_t)NOUT]   = acc[mi][ni][3] + bv;
    }
  }
}

extern "C" void kernel_launch(void* const* d_in, const int* in_sizes, int n_in,
                              void* d_out, int out_size, void* d_ws, size_t ws_size,
                              hipStream_t stream) {
  const float* x = (const float*)d_in[0];
  const float* G = (const float*)d_in[1];
  const float* H = (const float*)d_in[2];
  const float* bias = (const float*)d_in[3];
  float* out = (float*)d_out;

  __bf16* xb = (__bf16*)d_ws;                                    // 8 MB
  __bf16* Mb = (__bf16*)((char*)d_ws + (size_t)NTOK * NIN * 2);  // 8 MB

  prep_kernel<<<2048 + 2047, 256, 0, stream>>>(x, G, H, xb, Mb);
  gemm_kernel<<<256, 512, 0, stream>>>(xb, Mb, bias, out);
}